// Round 1
// baseline (176.130 us; speedup 1.0000x reference)
//
#include <hip/hip_runtime.h>

#define NF 64

// workspace float offsets
#define OFF_NORMG   0          // 2048
#define OFF_NORMP   2048       // 2048
#define OFF_SG      4096       // 2048
#define OFF_SP      6144       // 2048
#define OFF_MAXG    8192       // 1 (int bits)
#define OFF_MAXP    8193       // 1 (int bits)
#define OFF_U       8194       // 128
#define OFF_HSUMG   8322       // 256
#define OFF_HSUMP   8578       // 256
#define OFF_C1      8834       // 4
#define ZERO_FLOATS 8840
#define OFF_HA_G    9216
#define OFF_HA_P    140288
#define OFF_HB_G    271360
#define OFF_HB_P    402432
#define OFF_EG      533504
#define OFF_EP      664576
#define OFF_OBST    795648     // 1048576 floats

static __device__ __forceinline__ float wave_sum(float v) {
    for (int off = 32; off; off >>= 1) v += __shfl_down(v, off, 64);
    return v;
}

// ---------------- K1: transpose obs -> obsT, row/col nonzero counts ----------------
__global__ __launch_bounds__(256) void k_prep(const float* __restrict__ obs,
                                              float* __restrict__ ws) {
    __shared__ float tile[64][65];
    int b = blockIdx.y, t = threadIdx.x;
    int g0 = (blockIdx.x >> 3) * 64, p0 = (blockIdx.x & 7) * 64;
    int c = t & 63, r0 = t >> 6;   // r0 = wave id (0..3)
    const float* src = obs + ((size_t)b * 512 + g0) * 512 + p0;
    float* normg = ws + OFF_NORMG + b * 512 + g0;
    float* normp = ws + OFF_NORMP + b * 512 + p0;
    float colcnt = 0.f;
#pragma unroll
    for (int i = 0; i < 16; ++i) {
        int r = r0 + 4 * i;
        float v = src[(size_t)r * 512 + c];
        tile[r][c] = v;
        float nz = (v != 0.f) ? 1.f : 0.f;
        colcnt += nz;
        nz = wave_sum(nz);
        if (c == 0) atomicAdd(&normg[r], nz);
    }
    atomicAdd(&normp[c], colcnt);
    __syncthreads();
    float* dst = ws + OFF_OBST + ((size_t)b * 512 + p0) * 512 + g0;
#pragma unroll
    for (int i = 0; i < 16; ++i) {
        int pr = r0 + 4 * i;
        dst[(size_t)pr * 512 + c] = tile[c][pr];
    }
}

// ---------------- K2: S sums (masked weighted), global maxes, U precompute ----------------
__global__ __launch_bounds__(256) void k_s(const float* __restrict__ obs,
                                           float* __restrict__ ws,
                                           const float* __restrict__ Wee_g,
                                           const float* __restrict__ Wef_g,
                                           const float* __restrict__ Wee_p,
                                           const float* __restrict__ Wef_p) {
    int bid = blockIdx.x;
    if (bid == 1024) {  // U[side][f] = sum_e relu(Wee[e]) * Wef[e][f]
        int t = threadIdx.x;
        if (t < 128) {
            int side = t >> 6, f = t & 63;
            const float* Wee = side ? Wee_p : Wee_g;
            const float* Wef = side ? Wef_p : Wef_g;
            float u = 0.f;
#pragma unroll
            for (int e = 0; e < 63; ++e) u += fmaxf(Wee[e], 0.f) * Wef[e * 64 + f];
            ws[OFF_U + t] = u;
        }
        return;
    }
    int t = threadIdx.x, w = t >> 6, lane = t & 63;
    int row = bid * 4 + w;          // 0..4095
    int side = row >> 11;           // 0 = g rows, 1 = p rows
    int lr = row & 2047;            // b*512 + r
    int b = lr >> 9;
    const float* arow = side ? (ws + OFF_OBST + (size_t)lr * 512)
                             : (obs + (size_t)lr * 512);
    const float* wnorm = ws + (side ? OFF_NORMG : OFF_NORMP) + b * 512;
    float s = 0.f;
#pragma unroll
    for (int k = 0; k < 8; ++k) {
        int p = lane + 64 * k;
        float v = arow[p];
        if (v != 0.f) s += wnorm[p];
    }
    s = wave_sum(s) * (1.f / 512.f);
    if (lane == 0) {
        ws[(side ? OFF_SP : OFF_SG) + lr] = s;
        float nrm = ws[(side ? OFF_NORMP : OFF_NORMG) + lr];
        atomicMax((int*)&ws[side ? OFF_MAXP : OFF_MAXG], (int)nrm);
    }
}

// ---------------- K3: init h and e (edge embedding collapsed) ----------------
__global__ __launch_bounds__(256) void k_init(const float* __restrict__ Wi_g,
                                              const float* __restrict__ Wi_p,
                                              const float* __restrict__ Wef_g,
                                              const float* __restrict__ Wef_p,
                                              float* __restrict__ ws) {
    int idx = blockIdx.x * 256 + threadIdx.x;  // 0..262143
    int row = idx >> 6, f = idx & 63;
    int side = row >> 11, lr = row & 2047;
    float norm = ws[(side ? OFF_NORMP : OFF_NORMG) + lr];
    float nf1 = norm > 0.f ? norm : 1.f;
    float nf = norm * (1.f / 512.f);
    const float* Wi = side ? Wi_p : Wi_g;
    float h = fmaxf(nf * Wi[f], 0.f);
    ws[(side ? OFF_HA_P : OFF_HA_G) + (size_t)lr * 64 + f] = h;
    float A = ws[(side ? OFF_SP : OFF_SG) + lr] / nf1;
    int mx;
    {   float tmpf = ws[side ? OFF_MAXP : OFF_MAXG];
        mx = __float_as_int(tmpf); }
    float maxnf = (float)(mx > 1 ? mx : 1);
    float C = norm / maxnf;
    float U = ws[OFF_U + side * 64 + f];
    const float* Wef = side ? Wef_p : Wef_g;
    float e = fmaxf(A * U + C * Wef[63 * 64 + f], 0.f);
    ws[(side ? OFF_EP : OFF_EG) + (size_t)lr * 64 + f] = e;
}

// ---------------- K4: one MPNN layer, both sides. 256 blocks x 256 threads ----------------
__global__ __launch_bounds__(256) void k_layer(const float* __restrict__ obs,
                                               float* __restrict__ ws,
                                               const float* __restrict__ Wmsg_g,
                                               const float* __restrict__ Wupd_g,
                                               const float* __restrict__ Wmsg_p,
                                               const float* __restrict__ Wupd_p,
                                               int layer, int hin_g, int hin_p,
                                               int hout_g, int hout_p, int do_pool) {
    __shared__ float h_lds[128][NF];     // 32 KB staged chunk of opposite-side h
    __shared__ float agg_lds[16][NF];
    __shared__ float m_lds[16][NF];

    int side = blockIdx.x >> 7, tilei = blockIdx.x & 127;
    int row0 = tilei * 16;              // row index within side (= b*512 + r)
    int b = row0 >> 9;
    const float* adj   = side ? (ws + OFF_OBST + (size_t)row0 * 512)
                              : (obs + (size_t)row0 * 512);
    const float* h_opp = ws + (side ? hin_g : hin_p) + (size_t)b * 32768;
    const float* h_self= ws + (side ? hin_p : hin_g) + (size_t)row0 * 64;
    const float* e_b   = ws + (side ? OFF_EP : OFF_EG) + (size_t)row0 * 64;
    const float* nrm   = ws + (side ? OFF_NORMP : OFF_NORMG) + row0;
    const float* Wm    = (side ? Wmsg_p : Wmsg_g) + layer * 8192;
    const float* Wu    = (side ? Wupd_p : Wupd_g) + layer * 8192;
    float* h_out = ws + (side ? hout_p : hout_g) + (size_t)row0 * 64;
    float* hsum  = ws + (side ? OFF_HSUMP : OFF_HSUMG) + b * 64;

    int t = threadIdx.x, f = t & 63, rh = t >> 6;   // rows rh, rh+4, rh+8, rh+12
    float acc0 = 0.f, acc1 = 0.f, acc2 = 0.f, acc3 = 0.f;

    for (int pc = 0; pc < 4; ++pc) {
        __syncthreads();
        {   // stage h chunk [128][64]
            const float4* src = (const float4*)(h_opp + pc * 8192);
            float4* dst = (float4*)&h_lds[0][0];
#pragma unroll
            for (int i = 0; i < 8; ++i) dst[t + 256 * i] = src[t + 256 * i];
        }
        __syncthreads();
        const float4* a0 = (const float4*)(adj + (size_t)(rh + 0) * 512 + pc * 128);
        const float4* a1 = (const float4*)(adj + (size_t)(rh + 4) * 512 + pc * 128);
        const float4* a2 = (const float4*)(adj + (size_t)(rh + 8) * 512 + pc * 128);
        const float4* a3 = (const float4*)(adj + (size_t)(rh + 12) * 512 + pc * 128);
#pragma unroll 4
        for (int p4 = 0; p4 < 32; ++p4) {
            float4 o0 = a0[p4], o1 = a1[p4], o2 = a2[p4], o3 = a3[p4];
#pragma unroll
            for (int j = 0; j < 4; ++j) {
                float hv = h_lds[p4 * 4 + j][f];
                acc0 += ((const float*)&o0)[j] * hv;
                acc1 += ((const float*)&o1)[j] * hv;
                acc2 += ((const float*)&o2)[j] * hv;
                acc3 += ((const float*)&o3)[j] * hv;
            }
        }
    }
    acc0 *= 1.f / fmaxf(nrm[rh + 0], 1.f);
    acc1 *= 1.f / fmaxf(nrm[rh + 4], 1.f);
    acc2 *= 1.f / fmaxf(nrm[rh + 8], 1.f);
    acc3 *= 1.f / fmaxf(nrm[rh + 12], 1.f);
    agg_lds[rh + 0][f] = acc0;
    agg_lds[rh + 4][f] = acc1;
    agg_lds[rh + 8][f] = acc2;
    agg_lds[rh + 12][f] = acc3;
    __syncthreads();

    // phase 2: m = relu([agg, e] @ Wm)
    float m0 = 0.f, m1 = 0.f, m2 = 0.f, m3 = 0.f;
#pragma unroll
    for (int k4 = 0; k4 < 16; ++k4) {
        float4 A0 = *(const float4*)&agg_lds[rh + 0][k4 * 4];
        float4 A1 = *(const float4*)&agg_lds[rh + 4][k4 * 4];
        float4 A2 = *(const float4*)&agg_lds[rh + 8][k4 * 4];
        float4 A3 = *(const float4*)&agg_lds[rh + 12][k4 * 4];
#pragma unroll
        for (int j = 0; j < 4; ++j) {
            float wa = Wm[(k4 * 4 + j) * 64 + f];
            m0 += ((const float*)&A0)[j] * wa;
            m1 += ((const float*)&A1)[j] * wa;
            m2 += ((const float*)&A2)[j] * wa;
            m3 += ((const float*)&A3)[j] * wa;
        }
    }
#pragma unroll
    for (int k4 = 0; k4 < 16; ++k4) {
        float4 E0 = *(const float4*)&e_b[(size_t)(rh + 0) * 64 + k4 * 4];
        float4 E1 = *(const float4*)&e_b[(size_t)(rh + 4) * 64 + k4 * 4];
        float4 E2 = *(const float4*)&e_b[(size_t)(rh + 8) * 64 + k4 * 4];
        float4 E3 = *(const float4*)&e_b[(size_t)(rh + 12) * 64 + k4 * 4];
#pragma unroll
        for (int j = 0; j < 4; ++j) {
            float we = Wm[(64 + k4 * 4 + j) * 64 + f];
            m0 += ((const float*)&E0)[j] * we;
            m1 += ((const float*)&E1)[j] * we;
            m2 += ((const float*)&E2)[j] * we;
            m3 += ((const float*)&E3)[j] * we;
        }
    }
    m_lds[rh + 0][f] = fmaxf(m0, 0.f);
    m_lds[rh + 4][f] = fmaxf(m1, 0.f);
    m_lds[rh + 8][f] = fmaxf(m2, 0.f);
    m_lds[rh + 12][f] = fmaxf(m3, 0.f);
    __syncthreads();

    // phase 3: h_new = relu([h, m] @ Wu)
    float h0 = 0.f, h1 = 0.f, h2 = 0.f, h3 = 0.f;
#pragma unroll
    for (int k4 = 0; k4 < 16; ++k4) {
        float4 H0 = *(const float4*)&h_self[(size_t)(rh + 0) * 64 + k4 * 4];
        float4 H1 = *(const float4*)&h_self[(size_t)(rh + 4) * 64 + k4 * 4];
        float4 H2 = *(const float4*)&h_self[(size_t)(rh + 8) * 64 + k4 * 4];
        float4 H3 = *(const float4*)&h_self[(size_t)(rh + 12) * 64 + k4 * 4];
#pragma unroll
        for (int j = 0; j < 4; ++j) {
            float wh = Wu[(k4 * 4 + j) * 64 + f];
            h0 += ((const float*)&H0)[j] * wh;
            h1 += ((const float*)&H1)[j] * wh;
            h2 += ((const float*)&H2)[j] * wh;
            h3 += ((const float*)&H3)[j] * wh;
        }
    }
#pragma unroll
    for (int k4 = 0; k4 < 16; ++k4) {
        float4 M0 = *(const float4*)&m_lds[rh + 0][k4 * 4];
        float4 M1 = *(const float4*)&m_lds[rh + 4][k4 * 4];
        float4 M2 = *(const float4*)&m_lds[rh + 8][k4 * 4];
        float4 M3 = *(const float4*)&m_lds[rh + 12][k4 * 4];
#pragma unroll
        for (int j = 0; j < 4; ++j) {
            float wm = Wu[(64 + k4 * 4 + j) * 64 + f];
            h0 += ((const float*)&M0)[j] * wm;
            h1 += ((const float*)&M1)[j] * wm;
            h2 += ((const float*)&M2)[j] * wm;
            h3 += ((const float*)&M3)[j] * wm;
        }
    }
    h0 = fmaxf(h0, 0.f); h1 = fmaxf(h1, 0.f); h2 = fmaxf(h2, 0.f); h3 = fmaxf(h3, 0.f);
    h_out[(size_t)(rh + 0) * 64 + f] = h0;
    h_out[(size_t)(rh + 4) * 64 + f] = h1;
    h_out[(size_t)(rh + 8) * 64 + f] = h2;
    h_out[(size_t)(rh + 12) * 64 + f] = h3;
    if (do_pool) atomicAdd(&hsum[f], h0 + h1 + h2 + h3);
}

// ---------------- K5: pooled readout constant c1[b] ----------------
__global__ __launch_bounds__(256) void k_pool(const float* __restrict__ Wpg,
                                              const float* __restrict__ Wpp,
                                              const float* __restrict__ Wro,
                                              const float* __restrict__ bro,
                                              float* __restrict__ ws) {
    int t = threadIdx.x;          // 256 = B*64
    int b = t >> 6, f = t & 63;
    const float* hsg = ws + OFF_HSUMG + b * 64;
    const float* hsp = ws + OFF_HSUMP + b * 64;
    float vg = 0.f, vp = 0.f;
#pragma unroll
    for (int k = 0; k < 64; ++k) {
        vg += (hsg[k] * (1.f / 512.f)) * Wpg[k * 64 + f];
        vp += (hsp[k] * (1.f / 512.f)) * Wpp[k * 64 + f];
    }
    float hp = fmaxf(vg + vp, 0.f);
    float c = wave_sum(hp * Wro[f]);
    if (f == 0) ws[OFF_C1 + b] = c + bro[0];
}

// ---------------- K6: out[b,g] = c1[b] + h_g[b,g,:] . Wro[64:128] ----------------
__global__ __launch_bounds__(256) void k_out(const float* __restrict__ Wro,
                                             const float* __restrict__ ws,
                                             float* __restrict__ out) {
    int idx = blockIdx.x * 256 + threadIdx.x;   // 0..2047
    int b = idx >> 9;
    const float4* hrow = (const float4*)(ws + OFF_HB_G + (size_t)idx * 64);
    float s = 0.f;
#pragma unroll
    for (int k4 = 0; k4 < 16; ++k4) {
        float4 h4 = hrow[k4];
        s += h4.x * Wro[64 + k4 * 4 + 0];
        s += h4.y * Wro[64 + k4 * 4 + 1];
        s += h4.z * Wro[64 + k4 * 4 + 2];
        s += h4.w * Wro[64 + k4 * 4 + 3];
    }
    out[idx] = ws[OFF_C1 + b] + s;
}

extern "C" void kernel_launch(void* const* d_in, const int* in_sizes, int n_in,
                              void* d_out, int out_size, void* d_ws, size_t ws_size,
                              hipStream_t stream) {
    const float* obs   = (const float*)d_in[0];
    const float* Wi_g  = (const float*)d_in[1];
    const float* Wi_p  = (const float*)d_in[2];
    const float* Wee_g = (const float*)d_in[3];
    const float* Wef_g = (const float*)d_in[4];
    const float* Wee_p = (const float*)d_in[5];
    const float* Wef_p = (const float*)d_in[6];
    const float* Wm_g  = (const float*)d_in[7];
    const float* Wu_g  = (const float*)d_in[8];
    const float* Wm_p  = (const float*)d_in[9];
    const float* Wu_p  = (const float*)d_in[10];
    const float* Wpg   = (const float*)d_in[11];
    const float* Wpp   = (const float*)d_in[12];
    const float* Wro   = (const float*)d_in[13];
    const float* bro   = (const float*)d_in[14];
    float* ws  = (float*)d_ws;
    float* out = (float*)d_out;

    hipMemsetAsync(ws, 0, ZERO_FLOATS * sizeof(float), stream);
    k_prep<<<dim3(64, 4), 256, 0, stream>>>(obs, ws);
    k_s<<<1025, 256, 0, stream>>>(obs, ws, Wee_g, Wef_g, Wee_p, Wef_p);
    k_init<<<1024, 256, 0, stream>>>(Wi_g, Wi_p, Wef_g, Wef_p, ws);
    k_layer<<<256, 256, 0, stream>>>(obs, ws, Wm_g, Wu_g, Wm_p, Wu_p,
                                     0, OFF_HA_G, OFF_HA_P, OFF_HB_G, OFF_HB_P, 0);
    k_layer<<<256, 256, 0, stream>>>(obs, ws, Wm_g, Wu_g, Wm_p, Wu_p,
                                     1, OFF_HB_G, OFF_HB_P, OFF_HA_G, OFF_HA_P, 0);
    k_layer<<<256, 256, 0, stream>>>(obs, ws, Wm_g, Wu_g, Wm_p, Wu_p,
                                     2, OFF_HA_G, OFF_HA_P, OFF_HB_G, OFF_HB_P, 1);
    k_pool<<<1, 256, 0, stream>>>(Wpg, Wpp, Wro, bro, ws);
    k_out<<<8, 256, 0, stream>>>(Wro, ws, out);
}

// Round 2
// 130.268 us; speedup vs baseline: 1.3521x; 1.3521x over previous
//
#include <hip/hip_runtime.h>

#define NF 64

// workspace float offsets
#define OFF_NORMG   0          // 2048
#define OFF_NORMP   2048       // 2048
#define OFF_SG      4096       // 2048
#define OFF_SP      6144       // 2048
#define OFF_MAXG    8192       // 1 (float)
#define OFF_MAXP    8193       // 1 (float)
#define OFF_U       8194       // 128
#define OFF_HSUMG   8322       // 256
#define OFF_HSUMP   8578       // 256
#define OFF_C1      8834       // 4
#define ZERO_FLOATS 8840
#define OFF_HA_G    9216
#define OFF_HA_P    140288
#define OFF_HB_G    271360
#define OFF_HB_P    402432
#define OFF_EG      533504
#define OFF_EP      664576
#define OFF_OBST    795648     // 1048576 floats

static __device__ __forceinline__ float wave_sum(float v) {
    for (int off = 32; off; off >>= 1) v += __shfl_down(v, off, 64);
    return v;
}
static __device__ __forceinline__ float wave_max(float v) {
    for (int off = 32; off; off >>= 1) v = fmaxf(v, __shfl_down(v, off, 64));
    return v;
}

// ---------------- K1: transpose obs -> obsT, row/col nonzero counts ----------------
__global__ __launch_bounds__(256) void k_prep(const float* __restrict__ obs,
                                              float* __restrict__ ws) {
    __shared__ float tile[64][65];
    int b = blockIdx.y, t = threadIdx.x;
    int g0 = (blockIdx.x >> 3) * 64, p0 = (blockIdx.x & 7) * 64;
    int c = t & 63, r0 = t >> 6;   // r0 = wave id (0..3)
    const float* src = obs + ((size_t)b * 512 + g0) * 512 + p0;
    float* normg = ws + OFF_NORMG + b * 512 + g0;
    float* normp = ws + OFF_NORMP + b * 512 + p0;
    float colcnt = 0.f;
#pragma unroll
    for (int i = 0; i < 16; ++i) {
        int r = r0 + 4 * i;
        float v = src[(size_t)r * 512 + c];
        tile[r][c] = v;
        float nz = (v != 0.f) ? 1.f : 0.f;
        colcnt += nz;
        nz = wave_sum(nz);
        if (c == 0) atomicAdd(&normg[r], nz);
    }
    atomicAdd(&normp[c], colcnt);
    __syncthreads();
    float* dst = ws + OFF_OBST + ((size_t)b * 512 + p0) * 512 + g0;
#pragma unroll
    for (int i = 0; i < 16; ++i) {
        int pr = r0 + 4 * i;
        dst[(size_t)pr * 512 + c] = tile[c][pr];
    }
}

// ---------------- K2: S sums; block 1024 does norm-maxes + U precompute ----------------
__global__ __launch_bounds__(256) void k_s(const float* __restrict__ obs,
                                           float* __restrict__ ws,
                                           const float* __restrict__ Wee_g,
                                           const float* __restrict__ Wef_g,
                                           const float* __restrict__ Wee_p,
                                           const float* __restrict__ Wef_p) {
    int bid = blockIdx.x;
    if (bid == 1024) {
        __shared__ float redg[4], redp[4];
        int t = threadIdx.x, lane = t & 63, w = t >> 6;
        // global maxes over the 2048 norms per side (no atomics)
        float mg = 0.f, mp = 0.f;
        for (int k = t; k < 2048; k += 256) {
            mg = fmaxf(mg, ws[OFF_NORMG + k]);
            mp = fmaxf(mp, ws[OFF_NORMP + k]);
        }
        mg = wave_max(mg);
        mp = wave_max(mp);
        if (lane == 0) { redg[w] = mg; redp[w] = mp; }
        __syncthreads();
        if (t == 0) {
            ws[OFF_MAXG] = fmaxf(fmaxf(redg[0], redg[1]), fmaxf(redg[2], redg[3]));
            ws[OFF_MAXP] = fmaxf(fmaxf(redp[0], redp[1]), fmaxf(redp[2], redp[3]));
        }
        // U[side][f] = sum_e relu(Wee[e]) * Wef[e][f]
        if (t < 128) {
            int side = t >> 6, f = t & 63;
            const float* Wee = side ? Wee_p : Wee_g;
            const float* Wef = side ? Wef_p : Wef_g;
            float u = 0.f;
#pragma unroll
            for (int e = 0; e < 63; ++e) u += fmaxf(Wee[e], 0.f) * Wef[e * 64 + f];
            ws[OFF_U + t] = u;
        }
        return;
    }
    int t = threadIdx.x, w = t >> 6, lane = t & 63;
    int row = bid * 4 + w;          // 0..4095
    int side = row >> 11;           // 0 = g rows, 1 = p rows
    int lr = row & 2047;            // b*512 + r
    int b = lr >> 9;
    const float* arow = side ? (ws + OFF_OBST + (size_t)lr * 512)
                             : (obs + (size_t)lr * 512);
    const float* wnorm = ws + (side ? OFF_NORMG : OFF_NORMP) + b * 512;
    float s = 0.f;
#pragma unroll
    for (int k = 0; k < 8; ++k) {
        int p = lane + 64 * k;
        float v = arow[p];
        if (v != 0.f) s += wnorm[p];
    }
    s = wave_sum(s) * (1.f / 512.f);
    if (lane == 0) ws[(side ? OFF_SP : OFF_SG) + lr] = s;
}

// ---------------- K3: init h and e (edge embedding collapsed) ----------------
__global__ __launch_bounds__(256) void k_init(const float* __restrict__ Wi_g,
                                              const float* __restrict__ Wi_p,
                                              const float* __restrict__ Wef_g,
                                              const float* __restrict__ Wef_p,
                                              float* __restrict__ ws) {
    int idx = blockIdx.x * 256 + threadIdx.x;  // 0..262143
    int row = idx >> 6, f = idx & 63;
    int side = row >> 11, lr = row & 2047;
    float norm = ws[(side ? OFF_NORMP : OFF_NORMG) + lr];
    float nf1 = norm > 0.f ? norm : 1.f;
    float nf = norm * (1.f / 512.f);
    const float* Wi = side ? Wi_p : Wi_g;
    float h = fmaxf(nf * Wi[f], 0.f);
    ws[(side ? OFF_HA_P : OFF_HA_G) + (size_t)lr * 64 + f] = h;
    float A = ws[(side ? OFF_SP : OFF_SG) + lr] / nf1;
    float maxnf = fmaxf(ws[side ? OFF_MAXP : OFF_MAXG], 1.f);
    float C = norm / maxnf;
    float U = ws[OFF_U + side * 64 + f];
    const float* Wef = side ? Wef_p : Wef_g;
    float e = fmaxf(A * U + C * Wef[63 * 64 + f], 0.f);
    ws[(side ? OFF_EP : OFF_EG) + (size_t)lr * 64 + f] = e;
}

// ---------------- K4: one MPNN layer, both sides. 256 blocks x 256 threads ----------------
__global__ __launch_bounds__(256) void k_layer(const float* __restrict__ obs,
                                               float* __restrict__ ws,
                                               const float* __restrict__ Wmsg_g,
                                               const float* __restrict__ Wupd_g,
                                               const float* __restrict__ Wmsg_p,
                                               const float* __restrict__ Wupd_p,
                                               int layer, int hin_g, int hin_p,
                                               int hout_g, int hout_p, int do_pool) {
    __shared__ float h_lds[128][NF];     // 32 KB staged chunk of opposite-side h
    __shared__ float agg_lds[16][NF];
    __shared__ float m_lds[16][NF];

    int side = blockIdx.x >> 7, tilei = blockIdx.x & 127;
    int row0 = tilei * 16;              // row index within side (= b*512 + r)
    int b = row0 >> 9;
    const float* adj   = side ? (ws + OFF_OBST + (size_t)row0 * 512)
                              : (obs + (size_t)row0 * 512);
    const float* h_opp = ws + (side ? hin_g : hin_p) + (size_t)b * 32768;
    const float* h_self= ws + (side ? hin_p : hin_g) + (size_t)row0 * 64;
    const float* e_b   = ws + (side ? OFF_EP : OFF_EG) + (size_t)row0 * 64;
    const float* nrm   = ws + (side ? OFF_NORMP : OFF_NORMG) + row0;
    const float* Wm    = (side ? Wmsg_p : Wmsg_g) + layer * 8192;
    const float* Wu    = (side ? Wupd_p : Wupd_g) + layer * 8192;
    float* h_out = ws + (side ? hout_p : hout_g) + (size_t)row0 * 64;
    float* hsum  = ws + (side ? OFF_HSUMP : OFF_HSUMG) + b * 64;

    int t = threadIdx.x, f = t & 63, rh = t >> 6;   // rows rh, rh+4, rh+8, rh+12
    float acc0 = 0.f, acc1 = 0.f, acc2 = 0.f, acc3 = 0.f;

    for (int pc = 0; pc < 4; ++pc) {
        __syncthreads();
        {   // stage h chunk [128][64]
            const float4* src = (const float4*)(h_opp + pc * 8192);
            float4* dst = (float4*)&h_lds[0][0];
#pragma unroll
            for (int i = 0; i < 8; ++i) dst[t + 256 * i] = src[t + 256 * i];
        }
        __syncthreads();
        const float4* a0 = (const float4*)(adj + (size_t)(rh + 0) * 512 + pc * 128);
        const float4* a1 = (const float4*)(adj + (size_t)(rh + 4) * 512 + pc * 128);
        const float4* a2 = (const float4*)(adj + (size_t)(rh + 8) * 512 + pc * 128);
        const float4* a3 = (const float4*)(adj + (size_t)(rh + 12) * 512 + pc * 128);
#pragma unroll 4
        for (int p4 = 0; p4 < 32; ++p4) {
            float4 o0 = a0[p4], o1 = a1[p4], o2 = a2[p4], o3 = a3[p4];
#pragma unroll
            for (int j = 0; j < 4; ++j) {
                float hv = h_lds[p4 * 4 + j][f];
                acc0 += ((const float*)&o0)[j] * hv;
                acc1 += ((const float*)&o1)[j] * hv;
                acc2 += ((const float*)&o2)[j] * hv;
                acc3 += ((const float*)&o3)[j] * hv;
            }
        }
    }
    acc0 *= 1.f / fmaxf(nrm[rh + 0], 1.f);
    acc1 *= 1.f / fmaxf(nrm[rh + 4], 1.f);
    acc2 *= 1.f / fmaxf(nrm[rh + 8], 1.f);
    acc3 *= 1.f / fmaxf(nrm[rh + 12], 1.f);
    agg_lds[rh + 0][f] = acc0;
    agg_lds[rh + 4][f] = acc1;
    agg_lds[rh + 8][f] = acc2;
    agg_lds[rh + 12][f] = acc3;
    __syncthreads();

    // phase 2: m = relu([agg, e] @ Wm)
    float m0 = 0.f, m1 = 0.f, m2 = 0.f, m3 = 0.f;
#pragma unroll
    for (int k4 = 0; k4 < 16; ++k4) {
        float4 A0 = *(const float4*)&agg_lds[rh + 0][k4 * 4];
        float4 A1 = *(const float4*)&agg_lds[rh + 4][k4 * 4];
        float4 A2 = *(const float4*)&agg_lds[rh + 8][k4 * 4];
        float4 A3 = *(const float4*)&agg_lds[rh + 12][k4 * 4];
#pragma unroll
        for (int j = 0; j < 4; ++j) {
            float wa = Wm[(k4 * 4 + j) * 64 + f];
            m0 += ((const float*)&A0)[j] * wa;
            m1 += ((const float*)&A1)[j] * wa;
            m2 += ((const float*)&A2)[j] * wa;
            m3 += ((const float*)&A3)[j] * wa;
        }
    }
#pragma unroll
    for (int k4 = 0; k4 < 16; ++k4) {
        float4 E0 = *(const float4*)&e_b[(size_t)(rh + 0) * 64 + k4 * 4];
        float4 E1 = *(const float4*)&e_b[(size_t)(rh + 4) * 64 + k4 * 4];
        float4 E2 = *(const float4*)&e_b[(size_t)(rh + 8) * 64 + k4 * 4];
        float4 E3 = *(const float4*)&e_b[(size_t)(rh + 12) * 64 + k4 * 4];
#pragma unroll
        for (int j = 0; j < 4; ++j) {
            float we = Wm[(64 + k4 * 4 + j) * 64 + f];
            m0 += ((const float*)&E0)[j] * we;
            m1 += ((const float*)&E1)[j] * we;
            m2 += ((const float*)&E2)[j] * we;
            m3 += ((const float*)&E3)[j] * we;
        }
    }
    m_lds[rh + 0][f] = fmaxf(m0, 0.f);
    m_lds[rh + 4][f] = fmaxf(m1, 0.f);
    m_lds[rh + 8][f] = fmaxf(m2, 0.f);
    m_lds[rh + 12][f] = fmaxf(m3, 0.f);
    __syncthreads();

    // phase 3: h_new = relu([h, m] @ Wu)
    float h0 = 0.f, h1 = 0.f, h2 = 0.f, h3 = 0.f;
#pragma unroll
    for (int k4 = 0; k4 < 16; ++k4) {
        float4 H0 = *(const float4*)&h_self[(size_t)(rh + 0) * 64 + k4 * 4];
        float4 H1 = *(const float4*)&h_self[(size_t)(rh + 4) * 64 + k4 * 4];
        float4 H2 = *(const float4*)&h_self[(size_t)(rh + 8) * 64 + k4 * 4];
        float4 H3 = *(const float4*)&h_self[(size_t)(rh + 12) * 64 + k4 * 4];
#pragma unroll
        for (int j = 0; j < 4; ++j) {
            float wh = Wu[(k4 * 4 + j) * 64 + f];
            h0 += ((const float*)&H0)[j] * wh;
            h1 += ((const float*)&H1)[j] * wh;
            h2 += ((const float*)&H2)[j] * wh;
            h3 += ((const float*)&H3)[j] * wh;
        }
    }
#pragma unroll
    for (int k4 = 0; k4 < 16; ++k4) {
        float4 M0 = *(const float4*)&m_lds[rh + 0][k4 * 4];
        float4 M1 = *(const float4*)&m_lds[rh + 4][k4 * 4];
        float4 M2 = *(const float4*)&m_lds[rh + 8][k4 * 4];
        float4 M3 = *(const float4*)&m_lds[rh + 12][k4 * 4];
#pragma unroll
        for (int j = 0; j < 4; ++j) {
            float wm = Wu[(64 + k4 * 4 + j) * 64 + f];
            h0 += ((const float*)&M0)[j] * wm;
            h1 += ((const float*)&M1)[j] * wm;
            h2 += ((const float*)&M2)[j] * wm;
            h3 += ((const float*)&M3)[j] * wm;
        }
    }
    h0 = fmaxf(h0, 0.f); h1 = fmaxf(h1, 0.f); h2 = fmaxf(h2, 0.f); h3 = fmaxf(h3, 0.f);
    h_out[(size_t)(rh + 0) * 64 + f] = h0;
    h_out[(size_t)(rh + 4) * 64 + f] = h1;
    h_out[(size_t)(rh + 8) * 64 + f] = h2;
    h_out[(size_t)(rh + 12) * 64 + f] = h3;
    if (do_pool) atomicAdd(&hsum[f], h0 + h1 + h2 + h3);
}

// ---------------- K5: pooled readout constant c1[b] ----------------
__global__ __launch_bounds__(256) void k_pool(const float* __restrict__ Wpg,
                                              const float* __restrict__ Wpp,
                                              const float* __restrict__ Wro,
                                              const float* __restrict__ bro,
                                              float* __restrict__ ws) {
    int t = threadIdx.x;          // 256 = B*64
    int b = t >> 6, f = t & 63;
    const float* hsg = ws + OFF_HSUMG + b * 64;
    const float* hsp = ws + OFF_HSUMP + b * 64;
    float vg = 0.f, vp = 0.f;
#pragma unroll
    for (int k = 0; k < 64; ++k) {
        vg += (hsg[k] * (1.f / 512.f)) * Wpg[k * 64 + f];
        vp += (hsp[k] * (1.f / 512.f)) * Wpp[k * 64 + f];
    }
    float hp = fmaxf(vg + vp, 0.f);
    float c = wave_sum(hp * Wro[f]);
    if (f == 0) ws[OFF_C1 + b] = c + bro[0];
}

// ---------------- K6: out[b,g] = c1[b] + h_g[b,g,:] . Wro[64:128] ----------------
__global__ __launch_bounds__(256) void k_out(const float* __restrict__ Wro,
                                             const float* __restrict__ ws,
                                             float* __restrict__ out) {
    int idx = blockIdx.x * 256 + threadIdx.x;   // 0..2047
    int b = idx >> 9;
    const float4* hrow = (const float4*)(ws + OFF_HB_G + (size_t)idx * 64);
    float s = 0.f;
#pragma unroll
    for (int k4 = 0; k4 < 16; ++k4) {
        float4 h4 = hrow[k4];
        s += h4.x * Wro[64 + k4 * 4 + 0];
        s += h4.y * Wro[64 + k4 * 4 + 1];
        s += h4.z * Wro[64 + k4 * 4 + 2];
        s += h4.w * Wro[64 + k4 * 4 + 3];
    }
    out[idx] = ws[OFF_C1 + b] + s;
}

extern "C" void kernel_launch(void* const* d_in, const int* in_sizes, int n_in,
                              void* d_out, int out_size, void* d_ws, size_t ws_size,
                              hipStream_t stream) {
    const float* obs   = (const float*)d_in[0];
    const float* Wi_g  = (const float*)d_in[1];
    const float* Wi_p  = (const float*)d_in[2];
    const float* Wee_g = (const float*)d_in[3];
    const float* Wef_g = (const float*)d_in[4];
    const float* Wee_p = (const float*)d_in[5];
    const float* Wef_p = (const float*)d_in[6];
    const float* Wm_g  = (const float*)d_in[7];
    const float* Wu_g  = (const float*)d_in[8];
    const float* Wm_p  = (const float*)d_in[9];
    const float* Wu_p  = (const float*)d_in[10];
    const float* Wpg   = (const float*)d_in[11];
    const float* Wpp   = (const float*)d_in[12];
    const float* Wro   = (const float*)d_in[13];
    const float* bro   = (const float*)d_in[14];
    float* ws  = (float*)d_ws;
    float* out = (float*)d_out;

    hipMemsetAsync(ws, 0, ZERO_FLOATS * sizeof(float), stream);
    k_prep<<<dim3(64, 4), 256, 0, stream>>>(obs, ws);
    k_s<<<1025, 256, 0, stream>>>(obs, ws, Wee_g, Wef_g, Wee_p, Wef_p);
    k_init<<<1024, 256, 0, stream>>>(Wi_g, Wi_p, Wef_g, Wef_p, ws);
    k_layer<<<256, 256, 0, stream>>>(obs, ws, Wm_g, Wu_g, Wm_p, Wu_p,
                                     0, OFF_HA_G, OFF_HA_P, OFF_HB_G, OFF_HB_P, 0);
    k_layer<<<256, 256, 0, stream>>>(obs, ws, Wm_g, Wu_g, Wm_p, Wu_p,
                                     1, OFF_HB_G, OFF_HB_P, OFF_HA_G, OFF_HA_P, 0);
    k_layer<<<256, 256, 0, stream>>>(obs, ws, Wm_g, Wu_g, Wm_p, Wu_p,
                                     2, OFF_HA_G, OFF_HA_P, OFF_HB_G, OFF_HB_P, 1);
    k_pool<<<1, 256, 0, stream>>>(Wpg, Wpp, Wro, bro, ws);
    k_out<<<8, 256, 0, stream>>>(Wro, ws, out);
}

// Round 3
// 126.099 us; speedup vs baseline: 1.3968x; 1.0331x over previous
//
#include <hip/hip_runtime.h>

#define NF 64

// workspace float offsets
#define OFF_NORMG   0          // 2048
#define OFF_NORMP   2048       // 2048
#define OFF_SG      4096       // 2048
#define OFF_SP      6144       // 2048
#define OFF_MAXG    8192       // 1 (float)
#define OFF_MAXP    8193       // 1 (float)
#define OFF_U       8194       // 128
#define OFF_HSUMG   8322       // 256
#define OFF_HSUMP   8578       // 256
#define OFF_C1      8834       // 4
#define OFF_NPG     9216       // 8*2048 partial row counts (g side)
#define OFF_NPP     25600      // 8*2048 partial col counts (p side)
#define OFF_HA_G    41984      // 131072
#define OFF_HA_P    173056
#define OFF_HB_G    304128
#define OFF_HB_P    435200
#define OFF_EG      566272
#define OFF_EP      697344
#define OFF_OBST    828416     // 1048576 floats

static __device__ __forceinline__ float wave_sum(float v) {
    for (int off = 32; off; off >>= 1) v += __shfl_down(v, off, 64);
    return v;
}
static __device__ __forceinline__ float wave_max(float v) {
    for (int off = 32; off; off >>= 1) v = fmaxf(v, __shfl_down(v, off, 64));
    return v;
}

// ---------------- K1: transpose obs -> obsT, partial row/col nonzero counts ----------------
// Atomic-free: each block writes its complete 64x64-tile partials to a private slot.
__global__ __launch_bounds__(256) void k_prep(const float* __restrict__ obs,
                                              float* __restrict__ ws) {
    __shared__ float tile[64][65];
    __shared__ float cc[4][64];
    int b = blockIdx.y, t = threadIdx.x;
    int tg = blockIdx.x >> 3, tp = blockIdx.x & 7;
    int g0 = tg * 64, p0 = tp * 64;
    int c = t & 63, r0 = t >> 6;   // r0 = wave id (0..3)
    const float* src = obs + ((size_t)b * 512 + g0) * 512 + p0;
    float colcnt = 0.f;
#pragma unroll
    for (int i = 0; i < 16; ++i) {
        int r = r0 + 4 * i;
        float v = src[(size_t)r * 512 + c];
        tile[r][c] = v;
        float nz = (v != 0.f) ? 1.f : 0.f;
        colcnt += nz;
        nz = wave_sum(nz);
        if (c == 0) ws[OFF_NPG + tp * 2048 + b * 512 + g0 + r] = nz;
    }
    cc[r0][c] = colcnt;
    __syncthreads();
    if (r0 == 0)
        ws[OFF_NPP + tg * 2048 + b * 512 + p0 + c] =
            cc[0][c] + cc[1][c] + cc[2][c] + cc[3][c];
    float* dst = ws + OFF_OBST + ((size_t)b * 512 + p0) * 512 + g0;
#pragma unroll
    for (int i = 0; i < 16; ++i) {
        int pr = r0 + 4 * i;
        dst[(size_t)pr * 512 + c] = tile[c][pr];
    }
}

// ---------------- K1b: reduce partials -> norms; zero HSUM ----------------
__global__ __launch_bounds__(256) void k_norm(float* __restrict__ ws) {
    int bid = blockIdx.x;
    if (bid == 16) {
        int t = threadIdx.x;
        ws[OFF_HSUMG + t] = 0.f;
        ws[OFF_HSUMP + t] = 0.f;
        return;
    }
    int idx = bid * 256 + threadIdx.x;   // 0..4095
    int side = idx >> 11, lr = idx & 2047;
    const float* part = ws + (side ? OFF_NPP : OFF_NPG) + lr;
    float s = 0.f;
#pragma unroll
    for (int j = 0; j < 8; ++j) s += part[j * 2048];
    ws[(side ? OFF_NORMP : OFF_NORMG) + lr] = s;
}

// ---------------- K2: S sums; block 1024 does norm-maxes + U precompute ----------------
__global__ __launch_bounds__(256) void k_s(const float* __restrict__ obs,
                                           float* __restrict__ ws,
                                           const float* __restrict__ Wee_g,
                                           const float* __restrict__ Wef_g,
                                           const float* __restrict__ Wee_p,
                                           const float* __restrict__ Wef_p) {
    int bid = blockIdx.x;
    if (bid == 1024) {
        __shared__ float redg[4], redp[4];
        int t = threadIdx.x, lane = t & 63, w = t >> 6;
        float mg = 0.f, mp = 0.f;
        for (int k = t; k < 2048; k += 256) {
            mg = fmaxf(mg, ws[OFF_NORMG + k]);
            mp = fmaxf(mp, ws[OFF_NORMP + k]);
        }
        mg = wave_max(mg);
        mp = wave_max(mp);
        if (lane == 0) { redg[w] = mg; redp[w] = mp; }
        __syncthreads();
        if (t == 0) {
            ws[OFF_MAXG] = fmaxf(fmaxf(redg[0], redg[1]), fmaxf(redg[2], redg[3]));
            ws[OFF_MAXP] = fmaxf(fmaxf(redp[0], redp[1]), fmaxf(redp[2], redp[3]));
        }
        if (t < 128) {
            int side = t >> 6, f = t & 63;
            const float* Wee = side ? Wee_p : Wee_g;
            const float* Wef = side ? Wef_p : Wef_g;
            float u = 0.f;
#pragma unroll
            for (int e = 0; e < 63; ++e) u += fmaxf(Wee[e], 0.f) * Wef[e * 64 + f];
            ws[OFF_U + t] = u;
        }
        return;
    }
    int t = threadIdx.x, w = t >> 6, lane = t & 63;
    int row = bid * 4 + w;          // 0..4095
    int side = row >> 11;           // 0 = g rows, 1 = p rows
    int lr = row & 2047;            // b*512 + r
    int b = lr >> 9;
    const float* arow = side ? (ws + OFF_OBST + (size_t)lr * 512)
                             : (obs + (size_t)lr * 512);
    const float* wnorm = ws + (side ? OFF_NORMG : OFF_NORMP) + b * 512;
    float s = 0.f;
#pragma unroll
    for (int k = 0; k < 8; ++k) {
        int p = lane + 64 * k;
        float v = arow[p];
        if (v != 0.f) s += wnorm[p];
    }
    s = wave_sum(s) * (1.f / 512.f);
    if (lane == 0) ws[(side ? OFF_SP : OFF_SG) + lr] = s;
}

// ---------------- K3: init h and e (edge embedding collapsed) ----------------
__global__ __launch_bounds__(256) void k_init(const float* __restrict__ Wi_g,
                                              const float* __restrict__ Wi_p,
                                              const float* __restrict__ Wef_g,
                                              const float* __restrict__ Wef_p,
                                              float* __restrict__ ws) {
    int idx = blockIdx.x * 256 + threadIdx.x;  // 0..262143
    int row = idx >> 6, f = idx & 63;
    int side = row >> 11, lr = row & 2047;
    float norm = ws[(side ? OFF_NORMP : OFF_NORMG) + lr];
    float nf1 = norm > 0.f ? norm : 1.f;
    float nf = norm * (1.f / 512.f);
    const float* Wi = side ? Wi_p : Wi_g;
    float h = fmaxf(nf * Wi[f], 0.f);
    ws[(side ? OFF_HA_P : OFF_HA_G) + (size_t)lr * 64 + f] = h;
    float A = ws[(side ? OFF_SP : OFF_SG) + lr] / nf1;
    float maxnf = fmaxf(ws[side ? OFF_MAXP : OFF_MAXG], 1.f);
    float C = norm / maxnf;
    float U = ws[OFF_U + side * 64 + f];
    const float* Wef = side ? Wef_p : Wef_g;
    float e = fmaxf(A * U + C * Wef[63 * 64 + f], 0.f);
    ws[(side ? OFF_EP : OFF_EG) + (size_t)lr * 64 + f] = e;
}

// ---------------- K4: one MPNN layer, both sides. 256 blocks x 256 threads ----------------
__global__ __launch_bounds__(256) void k_layer(const float* __restrict__ obs,
                                               float* __restrict__ ws,
                                               const float* __restrict__ Wmsg_g,
                                               const float* __restrict__ Wupd_g,
                                               const float* __restrict__ Wmsg_p,
                                               const float* __restrict__ Wupd_p,
                                               int layer, int hin_g, int hin_p,
                                               int hout_g, int hout_p, int do_pool) {
    __shared__ float h_lds[128][NF];     // 32 KB staged chunk of opposite-side h
    __shared__ float agg_lds[16][NF];
    __shared__ float m_lds[16][NF];

    int side = blockIdx.x >> 7, tilei = blockIdx.x & 127;
    int row0 = tilei * 16;              // row index within side (= b*512 + r)
    int b = row0 >> 9;
    const float* adj   = side ? (ws + OFF_OBST + (size_t)row0 * 512)
                              : (obs + (size_t)row0 * 512);
    const float* h_opp = ws + (side ? hin_g : hin_p) + (size_t)b * 32768;
    const float* h_self= ws + (side ? hin_p : hin_g) + (size_t)row0 * 64;
    const float* e_b   = ws + (side ? OFF_EP : OFF_EG) + (size_t)row0 * 64;
    const float* nrm   = ws + (side ? OFF_NORMP : OFF_NORMG) + row0;
    const float* Wm    = (side ? Wmsg_p : Wmsg_g) + layer * 8192;
    const float* Wu    = (side ? Wupd_p : Wupd_g) + layer * 8192;
    float* h_out = ws + (side ? hout_p : hout_g) + (size_t)row0 * 64;
    float* hsum  = ws + (side ? OFF_HSUMP : OFF_HSUMG) + b * 64;

    int t = threadIdx.x, f = t & 63, rh = t >> 6;   // rows rh, rh+4, rh+8, rh+12
    float acc0 = 0.f, acc1 = 0.f, acc2 = 0.f, acc3 = 0.f;

    for (int pc = 0; pc < 4; ++pc) {
        __syncthreads();
        {   // stage h chunk [128][64]
            const float4* src = (const float4*)(h_opp + pc * 8192);
            float4* dst = (float4*)&h_lds[0][0];
#pragma unroll
            for (int i = 0; i < 8; ++i) dst[t + 256 * i] = src[t + 256 * i];
        }
        __syncthreads();
        const float4* a0 = (const float4*)(adj + (size_t)(rh + 0) * 512 + pc * 128);
        const float4* a1 = (const float4*)(adj + (size_t)(rh + 4) * 512 + pc * 128);
        const float4* a2 = (const float4*)(adj + (size_t)(rh + 8) * 512 + pc * 128);
        const float4* a3 = (const float4*)(adj + (size_t)(rh + 12) * 512 + pc * 128);
#pragma unroll 4
        for (int p4 = 0; p4 < 32; ++p4) {
            float4 o0 = a0[p4], o1 = a1[p4], o2 = a2[p4], o3 = a3[p4];
#pragma unroll
            for (int j = 0; j < 4; ++j) {
                float hv = h_lds[p4 * 4 + j][f];
                acc0 += ((const float*)&o0)[j] * hv;
                acc1 += ((const float*)&o1)[j] * hv;
                acc2 += ((const float*)&o2)[j] * hv;
                acc3 += ((const float*)&o3)[j] * hv;
            }
        }
    }
    acc0 *= 1.f / fmaxf(nrm[rh + 0], 1.f);
    acc1 *= 1.f / fmaxf(nrm[rh + 4], 1.f);
    acc2 *= 1.f / fmaxf(nrm[rh + 8], 1.f);
    acc3 *= 1.f / fmaxf(nrm[rh + 12], 1.f);
    agg_lds[rh + 0][f] = acc0;
    agg_lds[rh + 4][f] = acc1;
    agg_lds[rh + 8][f] = acc2;
    agg_lds[rh + 12][f] = acc3;
    __syncthreads();

    // phase 2: m = relu([agg, e] @ Wm)
    float m0 = 0.f, m1 = 0.f, m2 = 0.f, m3 = 0.f;
#pragma unroll
    for (int k4 = 0; k4 < 16; ++k4) {
        float4 A0 = *(const float4*)&agg_lds[rh + 0][k4 * 4];
        float4 A1 = *(const float4*)&agg_lds[rh + 4][k4 * 4];
        float4 A2 = *(const float4*)&agg_lds[rh + 8][k4 * 4];
        float4 A3 = *(const float4*)&agg_lds[rh + 12][k4 * 4];
#pragma unroll
        for (int j = 0; j < 4; ++j) {
            float wa = Wm[(k4 * 4 + j) * 64 + f];
            m0 += ((const float*)&A0)[j] * wa;
            m1 += ((const float*)&A1)[j] * wa;
            m2 += ((const float*)&A2)[j] * wa;
            m3 += ((const float*)&A3)[j] * wa;
        }
    }
#pragma unroll
    for (int k4 = 0; k4 < 16; ++k4) {
        float4 E0 = *(const float4*)&e_b[(size_t)(rh + 0) * 64 + k4 * 4];
        float4 E1 = *(const float4*)&e_b[(size_t)(rh + 4) * 64 + k4 * 4];
        float4 E2 = *(const float4*)&e_b[(size_t)(rh + 8) * 64 + k4 * 4];
        float4 E3 = *(const float4*)&e_b[(size_t)(rh + 12) * 64 + k4 * 4];
#pragma unroll
        for (int j = 0; j < 4; ++j) {
            float we = Wm[(64 + k4 * 4 + j) * 64 + f];
            m0 += ((const float*)&E0)[j] * we;
            m1 += ((const float*)&E1)[j] * we;
            m2 += ((const float*)&E2)[j] * we;
            m3 += ((const float*)&E3)[j] * we;
        }
    }
    m_lds[rh + 0][f] = fmaxf(m0, 0.f);
    m_lds[rh + 4][f] = fmaxf(m1, 0.f);
    m_lds[rh + 8][f] = fmaxf(m2, 0.f);
    m_lds[rh + 12][f] = fmaxf(m3, 0.f);
    __syncthreads();

    // phase 3: h_new = relu([h, m] @ Wu)
    float h0 = 0.f, h1 = 0.f, h2 = 0.f, h3 = 0.f;
#pragma unroll
    for (int k4 = 0; k4 < 16; ++k4) {
        float4 H0 = *(const float4*)&h_self[(size_t)(rh + 0) * 64 + k4 * 4];
        float4 H1 = *(const float4*)&h_self[(size_t)(rh + 4) * 64 + k4 * 4];
        float4 H2 = *(const float4*)&h_self[(size_t)(rh + 8) * 64 + k4 * 4];
        float4 H3 = *(const float4*)&h_self[(size_t)(rh + 12) * 64 + k4 * 4];
#pragma unroll
        for (int j = 0; j < 4; ++j) {
            float wh = Wu[(k4 * 4 + j) * 64 + f];
            h0 += ((const float*)&H0)[j] * wh;
            h1 += ((const float*)&H1)[j] * wh;
            h2 += ((const float*)&H2)[j] * wh;
            h3 += ((const float*)&H3)[j] * wh;
        }
    }
#pragma unroll
    for (int k4 = 0; k4 < 16; ++k4) {
        float4 M0 = *(const float4*)&m_lds[rh + 0][k4 * 4];
        float4 M1 = *(const float4*)&m_lds[rh + 4][k4 * 4];
        float4 M2 = *(const float4*)&m_lds[rh + 8][k4 * 4];
        float4 M3 = *(const float4*)&m_lds[rh + 12][k4 * 4];
#pragma unroll
        for (int j = 0; j < 4; ++j) {
            float wm = Wu[(64 + k4 * 4 + j) * 64 + f];
            h0 += ((const float*)&M0)[j] * wm;
            h1 += ((const float*)&M1)[j] * wm;
            h2 += ((const float*)&M2)[j] * wm;
            h3 += ((const float*)&M3)[j] * wm;
        }
    }
    h0 = fmaxf(h0, 0.f); h1 = fmaxf(h1, 0.f); h2 = fmaxf(h2, 0.f); h3 = fmaxf(h3, 0.f);
    h_out[(size_t)(rh + 0) * 64 + f] = h0;
    h_out[(size_t)(rh + 4) * 64 + f] = h1;
    h_out[(size_t)(rh + 8) * 64 + f] = h2;
    h_out[(size_t)(rh + 12) * 64 + f] = h3;
    if (do_pool) atomicAdd(&hsum[f], h0 + h1 + h2 + h3);
}

// ---------------- K5: pooled readout constant c1[b] ----------------
__global__ __launch_bounds__(256) void k_pool(const float* __restrict__ Wpg,
                                              const float* __restrict__ Wpp,
                                              const float* __restrict__ Wro,
                                              const float* __restrict__ bro,
                                              float* __restrict__ ws) {
    int t = threadIdx.x;          // 256 = B*64
    int b = t >> 6, f = t & 63;
    const float* hsg = ws + OFF_HSUMG + b * 64;
    const float* hsp = ws + OFF_HSUMP + b * 64;
    float vg = 0.f, vp = 0.f;
#pragma unroll
    for (int k = 0; k < 64; ++k) {
        vg += (hsg[k] * (1.f / 512.f)) * Wpg[k * 64 + f];
        vp += (hsp[k] * (1.f / 512.f)) * Wpp[k * 64 + f];
    }
    float hp = fmaxf(vg + vp, 0.f);
    float c = wave_sum(hp * Wro[f]);
    if (f == 0) ws[OFF_C1 + b] = c + bro[0];
}

// ---------------- K6: out[b,g] = c1[b] + h_g[b,g,:] . Wro[64:128] ----------------
__global__ __launch_bounds__(256) void k_out(const float* __restrict__ Wro,
                                             const float* __restrict__ ws,
                                             float* __restrict__ out) {
    int idx = blockIdx.x * 256 + threadIdx.x;   // 0..2047
    int b = idx >> 9;
    const float4* hrow = (const float4*)(ws + OFF_HB_G + (size_t)idx * 64);
    float s = 0.f;
#pragma unroll
    for (int k4 = 0; k4 < 16; ++k4) {
        float4 h4 = hrow[k4];
        s += h4.x * Wro[64 + k4 * 4 + 0];
        s += h4.y * Wro[64 + k4 * 4 + 1];
        s += h4.z * Wro[64 + k4 * 4 + 2];
        s += h4.w * Wro[64 + k4 * 4 + 3];
    }
    out[idx] = ws[OFF_C1 + b] + s;
}

extern "C" void kernel_launch(void* const* d_in, const int* in_sizes, int n_in,
                              void* d_out, int out_size, void* d_ws, size_t ws_size,
                              hipStream_t stream) {
    const float* obs   = (const float*)d_in[0];
    const float* Wi_g  = (const float*)d_in[1];
    const float* Wi_p  = (const float*)d_in[2];
    const float* Wee_g = (const float*)d_in[3];
    const float* Wef_g = (const float*)d_in[4];
    const float* Wee_p = (const float*)d_in[5];
    const float* Wef_p = (const float*)d_in[6];
    const float* Wm_g  = (const float*)d_in[7];
    const float* Wu_g  = (const float*)d_in[8];
    const float* Wm_p  = (const float*)d_in[9];
    const float* Wu_p  = (const float*)d_in[10];
    const float* Wpg   = (const float*)d_in[11];
    const float* Wpp   = (const float*)d_in[12];
    const float* Wro   = (const float*)d_in[13];
    const float* bro   = (const float*)d_in[14];
    float* ws  = (float*)d_ws;
    float* out = (float*)d_out;

    k_prep<<<dim3(64, 4), 256, 0, stream>>>(obs, ws);
    k_norm<<<17, 256, 0, stream>>>(ws);
    k_s<<<1025, 256, 0, stream>>>(obs, ws, Wee_g, Wef_g, Wee_p, Wef_p);
    k_init<<<1024, 256, 0, stream>>>(Wi_g, Wi_p, Wef_g, Wef_p, ws);
    k_layer<<<256, 256, 0, stream>>>(obs, ws, Wm_g, Wu_g, Wm_p, Wu_p,
                                     0, OFF_HA_G, OFF_HA_P, OFF_HB_G, OFF_HB_P, 0);
    k_layer<<<256, 256, 0, stream>>>(obs, ws, Wm_g, Wu_g, Wm_p, Wu_p,
                                     1, OFF_HB_G, OFF_HB_P, OFF_HA_G, OFF_HA_P, 0);
    k_layer<<<256, 256, 0, stream>>>(obs, ws, Wm_g, Wu_g, Wm_p, Wu_p,
                                     2, OFF_HA_G, OFF_HA_P, OFF_HB_G, OFF_HB_P, 1);
    k_pool<<<1, 256, 0, stream>>>(Wpg, Wpp, Wro, bro, ws);
    k_out<<<8, 256, 0, stream>>>(Wro, ws, out);
}